// Round 4
// baseline (640.160 us; speedup 1.0000x reference)
//
#include <hip/hip_runtime.h>
#include <hip/hip_bf16.h>

#define NN 100000
#define EE 1600000
#define HH 128
#define OUTC 10
#define BB 500
#define GSZ 200
#define LDA 136   // 128 + 8 bf16 pad (row stride 272B = 17*16B: 16B-aligned, conflict-free)

#define NBKT 782          // ceil(NN/128)
#define BCAP 2560
#define EPB 4096
#define NTILE 782         // ceil(NN/128) node tiles for fused layer kernel

typedef float f32x4 __attribute__((ext_vector_type(4)));
typedef __bf16 bf16x8 __attribute__((ext_vector_type(8)));

__device__ __forceinline__ float b2f(unsigned short u){
    unsigned int x = ((unsigned int)u) << 16;
    return __builtin_bit_cast(float, x);
}
__device__ __forceinline__ unsigned short f2b(float f){
    __hip_bfloat16 h = __float2bfloat16(f);
    return __builtin_bit_cast(unsigned short, h);
}

// ---------------- CSR build: bucketed counting sort ----------------
__global__ __launch_bounds__(256) void k_bucket(const int* __restrict__ src, const int* __restrict__ dst,
                                                int* __restrict__ bucket_cursor, unsigned int* __restrict__ ebuf){
    __shared__ unsigned int val[EPB];
    __shared__ unsigned short bkt[EPB];
    __shared__ int hist[NBKT];
    int t = threadIdx.x;
    int e0 = blockIdx.x * EPB;
    for (int i = t; i < NBKT; i += 256) hist[i] = 0;
    __syncthreads();
    for (int i = t; i < EPB; i += 256){
        int e = e0 + i;
        if (e < EE){
            int d = dst[e];
            int b = d >> 7;
            val[i] = ((unsigned)src[e] << 7) | (unsigned)(d & 127);
            bkt[i] = (unsigned short)b;
            atomicAdd(&hist[b], 1);
        } else {
            bkt[i] = 0xffff;
        }
    }
    __syncthreads();
    for (int i = t; i < NBKT; i += 256){
        int c = hist[i];
        hist[i] = c ? atomicAdd(&bucket_cursor[i], c) : 0;
    }
    __syncthreads();
    for (int i = t; i < EPB; i += 256){
        unsigned short b = bkt[i];
        if (b != 0xffff){
            int pos = atomicAdd(&hist[b], 1);
            if (pos < BCAP) ebuf[(int)b * BCAP + pos] = val[i];
        }
    }
}

__global__ __launch_bounds__(1024) void k_bscan(const int* __restrict__ bucket_cursor,
                                                int* __restrict__ bucket_base, int* __restrict__ row_ptr){
    __shared__ int tmp[1024];
    int t = threadIdx.x;
    int v = (t < NBKT) ? min(bucket_cursor[t], BCAP) : 0;
    tmp[t] = v; __syncthreads();
    for (int off = 1; off < 1024; off <<= 1){
        int a = (t >= off) ? tmp[t - off] : 0;
        __syncthreads();
        tmp[t] += a;
        __syncthreads();
    }
    if (t < NBKT) bucket_base[t + 1] = tmp[t];
    if (t == 0){ bucket_base[0] = 0; row_ptr[NN] = EE; }
}

__global__ __launch_bounds__(256) void k_csr(const int* __restrict__ bucket_cursor, const int* __restrict__ bucket_base,
                                             const unsigned int* __restrict__ ebuf,
                                             int* __restrict__ row_ptr, int* __restrict__ col){
    __shared__ int cnt[128];
    __shared__ int pfx[128];
    int b = blockIdx.x;
    int t = threadIdx.x;
    int c    = min(bucket_cursor[b], BCAP);
    int base = bucket_base[b];
    if (t < 128) cnt[t] = 0;
    __syncthreads();
    const unsigned int* eb = ebuf + (size_t)b * BCAP;
    for (int i = t; i < c; i += 256) atomicAdd(&cnt[eb[i] & 127], 1);
    __syncthreads();
    if (t == 0){
        int run = 0;
        for (int i = 0; i < 128; ++i){ pfx[i] = run; run += cnt[i]; }
    }
    __syncthreads();
    int node0 = b * 128;
    if (t < 128 && node0 + t < NN) row_ptr[node0 + t] = base + pfx[t];
    if (t < 128) cnt[t] = pfx[t];
    __syncthreads();
    for (int i = t; i < c; i += 256){
        unsigned int v = eb[i];
        int pos = atomicAdd(&cnt[v & 127], 1);
        col[base + pos] = (int)(v >> 7);
    }
}

// ---------------- weight prep: Wbf[w][n][k] = bf16(W_w[k][n]) ----------------
__global__ __launch_bounds__(256) void k_prep(const float* __restrict__ preW1, const float* __restrict__ preW2,
                                              const float* __restrict__ mlpW1, const float* __restrict__ mlpW2,
                                              unsigned short* __restrict__ Wbf){
    int idx = blockIdx.x*256 + threadIdx.x;   // 8*128*128
    int w = idx >> 14;
    int n = (idx >> 7) & 127;
    int k = idx & 127;
    const float* src;
    if      (w == 0) src = preW1;
    else if (w == 1) src = preW2;
    else if (w <  5) src = mlpW1 + (w-2)*16384;
    else             src = mlpW2 + (w-5)*16384;
    Wbf[idx] = f2b(src[k*128 + n]);
}

// ---------------- input: cast fp32->bf16 + graph pooling of reps[0], one pass ----------------
__global__ __launch_bounds__(256) void k_input(const float* __restrict__ x, unsigned short* __restrict__ hA,
                                               float* __restrict__ G){
    __shared__ float r0[256], r1[256];
    int t = threadIdx.x;
    int f2 = t & 63;
    int rg = t >> 6;
    int g  = blockIdx.x;
    float a0 = 0.f, a1 = 0.f;
    for (int i = rg; i < GSZ; i += 4){
        int node = g*GSZ + i;
        float2 v = *(const float2*)(x + (size_t)node*128 + f2*2);
        a0 += v.x; a1 += v.y;
        unsigned int o = (unsigned)f2b(v.x) | ((unsigned)f2b(v.y) << 16);
        ((unsigned int*)hA)[(size_t)node*64 + f2] = o;
    }
    r0[t] = a0; r1[t] = a1;
    __syncthreads();
    if (t < 64){
        float s0 = r0[t] + r0[t+64] + r0[t+128] + r0[t+192];
        float s1 = r1[t] + r1[t+64] + r1[t+128] + r1[t+192];
        float2 v; v.x = s0; v.y = s1;
        *(float2*)(G + g*128 + t*2) = v;
    }
}

// ---------------- gather helpers ----------------
__device__ __forceinline__ void acc_u32(float* a, unsigned int v, int j){
    a[j]   += __builtin_bit_cast(float, v << 16);
    a[j+1] += __builtin_bit_cast(float, v & 0xffff0000u);
}
__device__ __forceinline__ void acc_u4(float* a, uint4 v){
    acc_u32(a, v.x, 0); acc_u32(a, v.y, 2); acc_u32(a, v.z, 4); acc_u32(a, v.w, 6);
}
__device__ __forceinline__ void self_u4(float* a, uint4 hs, float ep){
    a[0] += ep * __builtin_bit_cast(float, hs.x << 16);
    a[1] += ep * __builtin_bit_cast(float, hs.x & 0xffff0000u);
    a[2] += ep * __builtin_bit_cast(float, hs.y << 16);
    a[3] += ep * __builtin_bit_cast(float, hs.y & 0xffff0000u);
    a[4] += ep * __builtin_bit_cast(float, hs.z << 16);
    a[5] += ep * __builtin_bit_cast(float, hs.z & 0xffff0000u);
    a[6] += ep * __builtin_bit_cast(float, hs.w << 16);
    a[7] += ep * __builtin_bit_cast(float, hs.w & 0xffff0000u);
}

// ---------------- fused GIN layer: gather-aggregate -> MLP(MFMA) -> graph pool ----------------
// 512 threads (8 waves), 128-node tile. LDS: As 17.4KB + Ws 34.8KB = 52.2KB... As is 128 rows: 34.8+34.8 = 69.6KB -> 2 blocks/CU
__global__ __launch_bounds__(512) void k_layer(const int* __restrict__ row_ptr, const int* __restrict__ col,
                                               const unsigned short* __restrict__ h,
                                               const float* __restrict__ eps, int l,
                                               unsigned short* __restrict__ Out,
                                               const unsigned short* __restrict__ W1t,
                                               const unsigned short* __restrict__ W2t,
                                               const float* __restrict__ b1, const float* __restrict__ g1,
                                               const float* __restrict__ bt1,
                                               const float* __restrict__ b2, const float* __restrict__ g2,
                                               const float* __restrict__ bt2,
                                               float* __restrict__ Gout){
    __shared__ __align__(16) unsigned short As[128*LDA];
    __shared__ __align__(16) unsigned short Ws[128*LDA];
    int t = threadIdx.x;
    int lane = t & 63, wv = t >> 6;          // wv 0..7
    int q = lane >> 4, u = lane & 15;
    int row0 = blockIdx.x * 128;
    float ep = 1.0f + eps[l];

    // ---- phase A: gather-aggregate 16 nodes per wave, paired for ILP ----
    for (int pi = 0; pi < 16; pi += 2){
        int lA = wv*16 + pi, lB = lA + 1;
        int nA = row0 + lA, nB = row0 + lB;
        bool vA = nA < NN, vB = nB < NN;
        float aA[8], aB[8];
        #pragma unroll
        for (int j = 0; j < 8; ++j){ aA[j] = 0.f; aB[j] = 0.f; }
        int eA = 0, endA = 0, eB = 0, endB = 0;
        uint4 hsA = make_uint4(0,0,0,0), hsB = make_uint4(0,0,0,0);
        if (vA){ eA = row_ptr[nA]; endA = row_ptr[nA+1]; }
        if (vB){ eB = row_ptr[nB]; endB = row_ptr[nB+1]; }
        if (vA && q == 0) hsA = *(const uint4*)(h + (size_t)nA*128 + u*8);
        if (vB && q == 0) hsB = *(const uint4*)(h + (size_t)nB*128 + u*8);

        while (eA + 8 <= endA && eB + 8 <= endB){
            int cA0 = col[eA + q], cA1 = col[eA + 4 + q];
            int cB0 = col[eB + q], cB1 = col[eB + 4 + q];
            uint4 xA0 = *(const uint4*)(h + (size_t)cA0*128 + u*8);
            uint4 xA1 = *(const uint4*)(h + (size_t)cA1*128 + u*8);
            uint4 xB0 = *(const uint4*)(h + (size_t)cB0*128 + u*8);
            uint4 xB1 = *(const uint4*)(h + (size_t)cB1*128 + u*8);
            acc_u4(aA, xA0); acc_u4(aA, xA1); acc_u4(aB, xB0); acc_u4(aB, xB1);
            eA += 8; eB += 8;
        }
        while (eA + 8 <= endA){
            int c0 = col[eA + q], c1 = col[eA + 4 + q];
            uint4 x0 = *(const uint4*)(h + (size_t)c0*128 + u*8);
            uint4 x1 = *(const uint4*)(h + (size_t)c1*128 + u*8);
            acc_u4(aA, x0); acc_u4(aA, x1);
            eA += 8;
        }
        while (eB + 8 <= endB){
            int c0 = col[eB + q], c1 = col[eB + 4 + q];
            uint4 x0 = *(const uint4*)(h + (size_t)c0*128 + u*8);
            uint4 x1 = *(const uint4*)(h + (size_t)c1*128 + u*8);
            acc_u4(aB, x0); acc_u4(aB, x1);
            eB += 8;
        }
        while (eA + 4 <= endA){
            int c = col[eA + q];
            uint4 x = *(const uint4*)(h + (size_t)c*128 + u*8);
            acc_u4(aA, x);
            eA += 4;
        }
        while (eB + 4 <= endB){
            int c = col[eB + q];
            uint4 x = *(const uint4*)(h + (size_t)c*128 + u*8);
            acc_u4(aB, x);
            eB += 4;
        }
        if (eA + q < endA){
            int c = col[eA + q];
            uint4 x = *(const uint4*)(h + (size_t)c*128 + u*8);
            acc_u4(aA, x);
        }
        if (eB + q < endB){
            int c = col[eB + q];
            uint4 x = *(const uint4*)(h + (size_t)c*128 + u*8);
            acc_u4(aB, x);
        }
        #pragma unroll
        for (int j = 0; j < 8; ++j){
            aA[j] += __shfl_xor(aA[j], 16, 64);
            aA[j] += __shfl_xor(aA[j], 32, 64);
            aB[j] += __shfl_xor(aB[j], 16, 64);
            aB[j] += __shfl_xor(aB[j], 32, 64);
        }
        if (q == 0){
            self_u4(aA, hsA, ep);     // hsA==0 for invalid nodes -> row stays 0
            self_u4(aB, hsB, ep);
            uint4 oA, oB;
            oA.x = (unsigned)f2b(aA[0]) | ((unsigned)f2b(aA[1]) << 16);
            oA.y = (unsigned)f2b(aA[2]) | ((unsigned)f2b(aA[3]) << 16);
            oA.z = (unsigned)f2b(aA[4]) | ((unsigned)f2b(aA[5]) << 16);
            oA.w = (unsigned)f2b(aA[6]) | ((unsigned)f2b(aA[7]) << 16);
            oB.x = (unsigned)f2b(aB[0]) | ((unsigned)f2b(aB[1]) << 16);
            oB.y = (unsigned)f2b(aB[2]) | ((unsigned)f2b(aB[3]) << 16);
            oB.z = (unsigned)f2b(aB[4]) | ((unsigned)f2b(aB[5]) << 16);
            oB.w = (unsigned)f2b(aB[6]) | ((unsigned)f2b(aB[7]) << 16);
            *(uint4*)(&As[lA*LDA + u*8]) = oA;
            *(uint4*)(&As[lB*LDA + u*8]) = oB;
        }
    }
    __syncthreads();

    // ---- phase B: MLP via MFMA ----
    for (int i = t; i < 128*16; i += 512){
        int r = i >> 4, c = i & 15;
        *(int4*)(&Ws[r*LDA + c*8]) = *(const int4*)(W1t + r*128 + c*8);
    }
    __syncthreads();

    int rowbase = wv * 16;
    int m = lane & 15;       // q already = lane>>4

    f32x4 acc[8];
    #pragma unroll
    for (int j = 0; j < 8; ++j) acc[j] = (f32x4){0.f,0.f,0.f,0.f};
    #pragma unroll
    for (int kk = 0; kk < 4; ++kk){
        bf16x8 a = *(const bf16x8*)(&As[(rowbase + m)*LDA + kk*32 + q*8]);
        #pragma unroll
        for (int j = 0; j < 8; ++j){
            bf16x8 b = *(const bf16x8*)(&Ws[(j*16 + m)*LDA + kk*32 + q*8]);
            acc[j] = __builtin_amdgcn_mfma_f32_16x16x32_bf16(a, b, acc[j], 0, 0, 0);
        }
    }
    #pragma unroll
    for (int j = 0; j < 8; ++j){
        int colc = j*16 + m;
        float bv = b1[colc], gv = g1[colc], btv = bt1[colc];
        #pragma unroll
        for (int r = 0; r < 4; ++r){
            float v = (acc[j][r] + bv)*gv + btv;
            v = fmaxf(v, 0.f);
            As[(rowbase + q*4 + r)*LDA + colc] = f2b(v);
        }
    }
    __syncthreads();
    for (int i = t; i < 128*16; i += 512){
        int r = i >> 4, c = i & 15;
        *(int4*)(&Ws[r*LDA + c*8]) = *(const int4*)(W2t + r*128 + c*8);
    }
    __syncthreads();

    #pragma unroll
    for (int j = 0; j < 8; ++j) acc[j] = (f32x4){0.f,0.f,0.f,0.f};
    #pragma unroll
    for (int kk = 0; kk < 4; ++kk){
        bf16x8 a = *(const bf16x8*)(&As[(rowbase + m)*LDA + kk*32 + q*8]);
        #pragma unroll
        for (int j = 0; j < 8; ++j){
            bf16x8 b = *(const bf16x8*)(&Ws[(j*16 + m)*LDA + kk*32 + q*8]);
            acc[j] = __builtin_amdgcn_mfma_f32_16x16x32_bf16(a, b, acc[j], 0, 0, 0);
        }
    }
    #pragma unroll
    for (int j = 0; j < 8; ++j){
        int colc = j*16 + m;
        float bv = b2[colc], gv = g2[colc], btv = bt2[colc];
        #pragma unroll
        for (int r = 0; r < 4; ++r){
            float v = (acc[j][r] + bv)*gv + btv;
            v = fmaxf(v, 0.f);
            As[(rowbase + q*4 + r)*LDA + colc] = f2b(v);
        }
    }
    __syncthreads();

    // ---- phase C: write out + fused graph pooling ----
    for (int i = t; i < 128*16; i += 512){
        int r = i >> 4, c = i & 15;
        int node = row0 + r;
        if (node < NN)
            *(int4*)(Out + node*128 + c*8) = *(const int4*)(&As[r*LDA + c*8]);
    }
    {
        int f = t & 127;
        int rbeg = (t >> 7) * 32;
        float run = 0.f;
        int curg = (row0 + rbeg) / GSZ;
        for (int r = rbeg; r < rbeg + 32; ++r){
            int node = row0 + r;
            if (node >= NN) break;
            int g = node / GSZ;
            if (g != curg){
                if (run != 0.f) atomicAdd(&Gout[curg*128 + f], run);
                run = 0.f; curg = g;
            }
            run += b2f(As[r*LDA + f]);
        }
        if (run != 0.f) atomicAdd(&Gout[curg*128 + f], run);
    }
}

// ---------------- score heads ----------------
__global__ __launch_bounds__(256) void k_score(const float* __restrict__ G,
                                               const float* __restrict__ W0, const float* __restrict__ b0,
                                               const float* __restrict__ Wk, const float* __restrict__ bk,
                                               float* __restrict__ out){
    int id = blockIdx.x*256 + threadIdx.x;
    if (id >= BB*OUTC) return;
    int b = id / OUTC, o = id % OUTC;
    float s = b0[o];
    #pragma unroll
    for (int k = 0; k < 4; ++k) s += bk[k*OUTC + o];
    const float* g0 = G + b*128;
    for (int c = 0; c < 128; ++c) s += g0[c] * W0[c*OUTC + o];
    for (int k = 0; k < 4; ++k){
        const float* gk = G + (size_t)(k+1)*BB*128 + b*128;
        const float* wk = Wk + k*128*OUTC;
        for (int c = 0; c < 128; ++c) s += gk[c] * wk[c*OUTC + o];
    }
    out[id] = s;
}

extern "C" void kernel_launch(void* const* d_in, const int* in_sizes, int n_in,
                              void* d_out, int out_size, void* d_ws, size_t ws_size,
                              hipStream_t stream){
    const float* node_features = (const float*)d_in[0];
    const int*   edge_src  = (const int*)d_in[1];
    const int*   edge_dst  = (const int*)d_in[2];
    const float* eps       = (const float*)d_in[4];
    const float* pre_W1    = (const float*)d_in[5];
    const float* pre_b1    = (const float*)d_in[6];
    const float* pre_g1    = (const float*)d_in[7];
    const float* pre_bt1   = (const float*)d_in[8];
    const float* pre_W2    = (const float*)d_in[9];
    const float* pre_b2    = (const float*)d_in[10];
    const float* pre_gout  = (const float*)d_in[11];
    const float* pre_btout = (const float*)d_in[12];
    const float* mlp_W1    = (const float*)d_in[13];
    const float* mlp_b1    = (const float*)d_in[14];
    const float* mlp_g1    = (const float*)d_in[15];
    const float* mlp_bt1   = (const float*)d_in[16];
    const float* mlp_W2    = (const float*)d_in[17];
    const float* mlp_b2    = (const float*)d_in[18];
    const float* bn_g      = (const float*)d_in[19];
    const float* bn_bt     = (const float*)d_in[20];
    const float* pred_W0   = (const float*)d_in[21];
    const float* pred_b0   = (const float*)d_in[22];
    const float* pred_W    = (const float*)d_in[23];
    const float* pred_b    = (const float*)d_in[24];
    float* out = (float*)d_out;

    char* p = (char*)d_ws;
    auto alloc = [&](size_t bytes)->char*{
        char* r = p;
        p += (bytes + 255) & ~(size_t)255;
        return r;
    };
    int* bucket_cursor    = (int*)alloc((size_t)NBKT*4);
    int* bucket_base      = (int*)alloc((size_t)(NBKT+1)*4);
    int* row_ptr          = (int*)alloc((size_t)(NN+1)*4);
    int* col              = (int*)alloc((size_t)EE*4);
    unsigned int* ebuf    = (unsigned int*)alloc((size_t)NBKT*BCAP*4);
    unsigned short* Wbf   = (unsigned short*)alloc((size_t)8*128*128*2);
    unsigned short* hA    = (unsigned short*)alloc((size_t)NN*128*2);
    unsigned short* hB    = (unsigned short*)alloc((size_t)NN*128*2);
    float* G              = (float*)alloc((size_t)5*BB*128*4);

    hipMemsetAsync(bucket_cursor, 0, (size_t)NBKT*4, stream);
    hipMemsetAsync(G, 0, (size_t)5*BB*128*4, stream);

    k_bucket<<<(EE + EPB - 1)/EPB, 256, 0, stream>>>(edge_src, edge_dst, bucket_cursor, ebuf);
    k_bscan<<<1, 1024, 0, stream>>>(bucket_cursor, bucket_base, row_ptr);
    k_csr<<<NBKT, 256, 0, stream>>>(bucket_cursor, bucket_base, ebuf, row_ptr, col);

    k_input<<<BB, 256, 0, stream>>>(node_features, hA, G);
    k_prep<<<512, 256, 0, stream>>>(pre_W1, pre_W2, mlp_W1, mlp_W2, Wbf);

    const unsigned short* hcur = hA;
    unsigned short* hnxt = hB;
    for (int l = 0; l < 4; ++l){
        const unsigned short *W1t, *W2t;
        const float *b1,*g1,*bt1,*b2,*g2,*bt2;
        if (l == 0){
            W1t = Wbf;             W2t = Wbf + 16384;
            b1 = pre_b1; g1 = pre_g1; bt1 = pre_bt1;
            b2 = pre_b2; g2 = pre_gout; bt2 = pre_btout;
        } else {
            W1t = Wbf + (size_t)(2 + (l-1))*16384;
            W2t = Wbf + (size_t)(5 + (l-1))*16384;
            b1 = mlp_b1 + (l-1)*128; g1 = mlp_g1 + (l-1)*128; bt1 = mlp_bt1 + (l-1)*128;
            b2 = mlp_b2 + (l-1)*128; g2 = bn_g   + (l-1)*128; bt2 = bn_bt   + (l-1)*128;
        }
        k_layer<<<NTILE, 512, 0, stream>>>(row_ptr, col, hcur, eps, l, hnxt, W1t, W2t,
                                           b1,g1,bt1, b2,g2,bt2,
                                           G + (size_t)(l+1)*BB*128);
        const unsigned short* tmp = hnxt;
        hnxt = (unsigned short*)hcur;
        hcur = tmp;
    }
    k_score<<<(BB*OUTC + 255)/256, 256, 0, stream>>>(G, pred_W0, pred_b0, pred_W, pred_b, out);
}